// Round 1
// baseline (1856.916 us; speedup 1.0000x reference)
//
#include <hip/hip_runtime.h>

#define NN 100000
#define F_IN 128
#define H1 100

// ---------------- degree / norm ----------------
__global__ void k_deg_init(float* __restrict__ deg, int n) {
    int i = blockIdx.x * blockDim.x + threadIdx.x;
    if (i < n) deg[i] = 1.0f;  // self-loop
}

__global__ void k_deg_count(const int* __restrict__ dst, float* __restrict__ deg, int E, int n) {
    int i = blockIdx.x * blockDim.x + threadIdx.x;
    if (i < E) {
        unsigned d = (unsigned)dst[i];
        if (d >= (unsigned)n) d = 0;  // defensive clamp
        atomicAdd(&deg[d], 1.0f);
    }
}

__global__ void k_dinv(float* __restrict__ deg, int n) {
    int i = blockIdx.x * blockDim.x + threadIdx.x;
    if (i < n) deg[i] = rsqrtf(deg[i]);  // deg >= 1 always
}

// ---------------- layer-1 GEMM: g = dinv * (x @ W1); acc1 = g (self-loop init) ----
// block: 128 threads (f = tid, active f < 100), 8 nodes per block.
__global__ __launch_bounds__(128) void k_gemm1(
    const float* __restrict__ x, const float* __restrict__ W1,
    const float* __restrict__ dinv,
    float* __restrict__ g, float* __restrict__ acc, int n) {
    __shared__ float xs[8][F_IN];
    const int f = threadIdx.x;
    const int nb = blockIdx.x * 8;

    // stage 8 x-rows (8*128 floats = 256 float4) into LDS, coalesced
    {
        const float4* xv = (const float4*)(x + (long)nb * F_IN);
        float4* xsv = (float4*)&xs[0][0];
        #pragma unroll
        for (int i = threadIdx.x; i < 256; i += 128) {
            int node = nb + (i >> 5);
            xsv[i] = (node < n) ? xv[i] : make_float4(0.f, 0.f, 0.f, 0.f);
        }
    }
    __syncthreads();

    const bool act = (f < H1);
    float a0 = 0.f, a1 = 0.f, a2 = 0.f, a3 = 0.f, a4 = 0.f, a5 = 0.f, a6 = 0.f, a7 = 0.f;
    float accv[8] = {0, 0, 0, 0, 0, 0, 0, 0};

    for (int kc = 0; kc < F_IN; kc += 8) {
        float w[8];
        #pragma unroll
        for (int j = 0; j < 8; ++j) w[j] = act ? W1[(kc + j) * H1 + f] : 0.0f;
        #pragma unroll
        for (int v = 0; v < 8; ++v) {
            const float4 b0 = *(const float4*)&xs[v][kc];
            const float4 b1 = *(const float4*)&xs[v][kc + 4];
            float s = accv[v];
            s = fmaf(b0.x, w[0], s);
            s = fmaf(b0.y, w[1], s);
            s = fmaf(b0.z, w[2], s);
            s = fmaf(b0.w, w[3], s);
            s = fmaf(b1.x, w[4], s);
            s = fmaf(b1.y, w[5], s);
            s = fmaf(b1.z, w[6], s);
            s = fmaf(b1.w, w[7], s);
            accv[v] = s;
        }
    }
    (void)a0; (void)a1; (void)a2; (void)a3; (void)a4; (void)a5; (void)a6; (void)a7;

    if (act) {
        #pragma unroll
        for (int v = 0; v < 8; ++v) {
            int node = nb + v;
            if (node < n) {
                float gv = accv[v] * dinv[node];
                g[(long)node * H1 + f] = gv;
                acc[(long)node * H1 + f] = gv;
            }
        }
    }
}

// ---------------- layer-1 edge scatter: acc1[dst] += g[src] ----------------
// 256 threads = 2 edges x 128 lanes (f = lane & 127, active f < 100)
__global__ __launch_bounds__(256) void k_scatter1(
    const int* __restrict__ src, const int* __restrict__ dst,
    const float* __restrict__ g, float* __restrict__ acc, int E, int n) {
    const int f = threadIdx.x & 127;
    const long e = (long)blockIdx.x * 2 + (threadIdx.x >> 7);
    if (e >= E || f >= H1) return;
    unsigned s = (unsigned)src[e];
    unsigned d = (unsigned)dst[e];
    if (s >= (unsigned)n) s = 0;
    if (d >= (unsigned)n) d = 0;
    atomicAdd(&acc[(long)d * H1 + f], g[(long)s * H1 + f]);
}

// ---------------- mid: s[v] = relu(dinv*acc1 + b1) . W2 ; g2 = dinv*s ; acc2 = g2 ----
// one wave (64 lanes) per node, 4 nodes per block
__global__ __launch_bounds__(256) void k_mid(
    const float* __restrict__ acc1, const float* __restrict__ dinv,
    const float* __restrict__ b1, const float* __restrict__ W2,
    float* __restrict__ g2, float* __restrict__ acc2, int n) {
    const int lane = threadIdx.x & 63;
    const int node = blockIdx.x * 4 + (threadIdx.x >> 6);
    if (node >= n) return;
    const float di = dinv[node];
    const float* a = acc1 + (long)node * H1;
    float sum = fmaxf(fmaf(di, a[lane], b1[lane]), 0.f) * W2[lane];
    if (lane < H1 - 64) {
        sum += fmaxf(fmaf(di, a[64 + lane], b1[64 + lane]), 0.f) * W2[64 + lane];
    }
    #pragma unroll
    for (int off = 32; off > 0; off >>= 1) sum += __shfl_down(sum, off);
    if (lane == 0) {
        float gv = di * sum;
        g2[node] = gv;
        acc2[node] = gv;
    }
}

// ---------------- layer-2 scalar edge scatter ----------------
__global__ void k_scatter2(const int* __restrict__ src, const int* __restrict__ dst,
                           const float* __restrict__ g2, float* __restrict__ acc2, int E, int n) {
    int i = blockIdx.x * blockDim.x + threadIdx.x;
    if (i < E) {
        unsigned s = (unsigned)src[i];
        unsigned d = (unsigned)dst[i];
        if (s >= (unsigned)n) s = 0;
        if (d >= (unsigned)n) d = 0;
        atomicAdd(&acc2[d], g2[s]);
    }
}

// ---------------- final: out = dinv*acc2 + b2 ----------------
__global__ void k_final(const float* __restrict__ acc2, const float* __restrict__ dinv,
                        const float* __restrict__ b2, float* __restrict__ out, int n) {
    int i = blockIdx.x * blockDim.x + threadIdx.x;
    if (i < n) out[i] = fmaf(dinv[i], acc2[i], b2[0]);
}

extern "C" void kernel_launch(void* const* d_in, const int* in_sizes, int n_in,
                              void* d_out, int out_size, void* d_ws, size_t ws_size,
                              hipStream_t stream) {
    const float* x  = (const float*)d_in[0];
    const int*   ei = (const int*)d_in[1];
    const float* W1 = (const float*)d_in[2];
    const float* b1 = (const float*)d_in[3];
    const float* W2 = (const float*)d_in[4];
    const float* b2 = (const float*)d_in[5];

    const int n = in_sizes[0] / F_IN;     // 100000
    const int E = in_sizes[1] / 2;        // 3200000
    const int* src = ei;
    const int* dst = ei + E;

    float* ws   = (float*)d_ws;
    float* dinv = ws;                      // n
    float* g1   = dinv + n;                // n*H1
    float* acc1 = g1 + (size_t)n * H1;     // n*H1
    float* g2   = acc1 + (size_t)n * H1;   // n
    float* acc2 = g2 + n;                  // n
    float* out  = (float*)d_out;

    k_deg_init<<<(n + 255) / 256, 256, 0, stream>>>(dinv, n);
    k_deg_count<<<(E + 255) / 256, 256, 0, stream>>>(dst, dinv, E, n);
    k_dinv<<<(n + 255) / 256, 256, 0, stream>>>(dinv, n);
    k_gemm1<<<(n + 7) / 8, 128, 0, stream>>>(x, W1, dinv, g1, acc1, n);
    k_scatter1<<<(E + 1) / 2, 256, 0, stream>>>(src, dst, g1, acc1, E, n);
    k_mid<<<(n + 3) / 4, 256, 0, stream>>>(acc1, dinv, b1, W2, g2, acc2, n);
    k_scatter2<<<(E + 255) / 256, 256, 0, stream>>>(src, dst, g2, acc2, E, n);
    k_final<<<(n + 255) / 256, 256, 0, stream>>>(acc2, dinv, b2, out, n);
}

// Round 3
// 701.880 us; speedup vs baseline: 2.6456x; 2.6456x over previous
//
#include <hip/hip_runtime.h>

#define F_IN 128
#define H1 100
#define SCAN_BLK 256
#define SCAN_CH 1024  // elements per scan block (4 per thread)

// ---------------- zero int buffers ----------------
__global__ void k_zero_i(int* __restrict__ p, int n) {
    int i = blockIdx.x * blockDim.x + threadIdx.x;
    if (i < n) p[i] = 0;
}

// ---------------- histogram of dst ----------------
__global__ void k_count(const int* __restrict__ dst, int* __restrict__ counts, int E, int n) {
    int i = blockIdx.x * blockDim.x + threadIdx.x;
    if (i < E) {
        unsigned d = (unsigned)dst[i];
        if (d >= (unsigned)n) d = 0;  // defensive clamp
        atomicAdd(&counts[d], 1);
    }
}

// ---------------- dinv = rsqrt(1 + count) ----------------
__global__ void k_dinv(const int* __restrict__ counts, float* __restrict__ dinv, int n) {
    int i = blockIdx.x * blockDim.x + threadIdx.x;
    if (i < n) dinv[i] = rsqrtf(1.0f + (float)counts[i]);
}

// ---------------- prefix-scan pass A: per-block sums ----------------
__global__ __launch_bounds__(SCAN_BLK) void k_blocksums(const int* __restrict__ counts,
                                                        int* __restrict__ bsum, int n) {
    __shared__ int sd[SCAN_BLK];
    const int tid = threadIdx.x;
    const int base = blockIdx.x * SCAN_CH + tid * 4;
    int s = 0;
    #pragma unroll
    for (int j = 0; j < 4; ++j) {
        int i = base + j;
        if (i < n) s += counts[i];
    }
    sd[tid] = s;
    __syncthreads();
    for (int off = SCAN_BLK / 2; off > 0; off >>= 1) {
        if (tid < off) sd[tid] += sd[tid + off];
        __syncthreads();
    }
    if (tid == 0) bsum[blockIdx.x] = sd[0];
}

// ---------------- pass B: exclusive scan of block sums (nb <= 128) ----------------
__global__ __launch_bounds__(128) void k_scan_bsums(int* __restrict__ bsum, int nb) {
    __shared__ int sd[128];
    const int tid = threadIdx.x;
    const int v = (tid < nb) ? bsum[tid] : 0;
    sd[tid] = v;
    __syncthreads();
    for (int off = 1; off < 128; off <<= 1) {
        int t = (tid >= off) ? sd[tid - off] : 0;
        __syncthreads();
        sd[tid] += t;
        __syncthreads();
    }
    if (tid < nb) bsum[tid] = sd[tid] - v;  // exclusive
}

// ---------------- pass C: write rowstart ----------------
__global__ __launch_bounds__(SCAN_BLK) void k_scan_write(const int* __restrict__ counts,
                                                         const int* __restrict__ bsum,
                                                         int* __restrict__ rowstart, int n) {
    __shared__ int sd[SCAN_BLK];
    const int tid = threadIdx.x;
    const int base = blockIdx.x * SCAN_CH + tid * 4;
    int c[4];
    int s = 0;
    #pragma unroll
    for (int j = 0; j < 4; ++j) {
        int i = base + j;
        c[j] = (i < n) ? counts[i] : 0;
        s += c[j];
    }
    const int own = s;
    sd[tid] = s;
    __syncthreads();
    for (int off = 1; off < SCAN_BLK; off <<= 1) {
        int t = (tid >= off) ? sd[tid - off] : 0;
        __syncthreads();
        sd[tid] += t;
        __syncthreads();
    }
    int pre = sd[tid] - own + bsum[blockIdx.x];
    #pragma unroll
    for (int j = 0; j < 4; ++j) {
        int i = base + j;
        if (i < n) {
            rowstart[i] = pre;
            pre += c[j];
        }
    }
}

// ---------------- CSR fill: bucket src indices by dst ----------------
__global__ void k_fill(const int* __restrict__ src, const int* __restrict__ dst,
                       const int* __restrict__ rowstart, int* __restrict__ cursor,
                       int* __restrict__ ebuf, int E, int n) {
    int i = blockIdx.x * blockDim.x + threadIdx.x;
    if (i < E) {
        unsigned d = (unsigned)dst[i];
        unsigned s = (unsigned)src[i];
        if (d >= (unsigned)n) d = 0;
        if (s >= (unsigned)n) s = 0;
        int pos = atomicAdd(&cursor[d], 1);
        ebuf[rowstart[d] + pos] = (int)s;
    }
}

// ---------------- layer-1 GEMM: g1 = dinv * (x @ W1) ----------------
// block: 128 threads (f = tid, active f < 100), 8 nodes per block.
__global__ __launch_bounds__(128) void k_gemm1(
    const float* __restrict__ x, const float* __restrict__ W1,
    const float* __restrict__ dinv, float* __restrict__ g, int n) {
    __shared__ float xs[8][F_IN];
    const int f = threadIdx.x;
    const int nb = blockIdx.x * 8;

    {
        const float4* xv = (const float4*)(x + (long)nb * F_IN);
        float4* xsv = (float4*)&xs[0][0];
        #pragma unroll
        for (int i = threadIdx.x; i < 256; i += 128) {
            int node = nb + (i >> 5);
            xsv[i] = (node < n) ? xv[i] : make_float4(0.f, 0.f, 0.f, 0.f);
        }
    }
    __syncthreads();

    const bool act = (f < H1);
    float accv[8] = {0, 0, 0, 0, 0, 0, 0, 0};

    for (int kc = 0; kc < F_IN; kc += 8) {
        float w[8];
        #pragma unroll
        for (int j = 0; j < 8; ++j) w[j] = act ? W1[(kc + j) * H1 + f] : 0.0f;
        #pragma unroll
        for (int v = 0; v < 8; ++v) {
            const float4 b0 = *(const float4*)&xs[v][kc];
            const float4 b1 = *(const float4*)&xs[v][kc + 4];
            float s = accv[v];
            s = fmaf(b0.x, w[0], s);
            s = fmaf(b0.y, w[1], s);
            s = fmaf(b0.z, w[2], s);
            s = fmaf(b0.w, w[3], s);
            s = fmaf(b1.x, w[4], s);
            s = fmaf(b1.y, w[5], s);
            s = fmaf(b1.z, w[6], s);
            s = fmaf(b1.w, w[7], s);
            accv[v] = s;
        }
    }

    if (act) {
        #pragma unroll
        for (int v = 0; v < 8; ++v) {
            int node = nb + v;
            if (node < n) g[(long)node * H1 + f] = accv[v] * dinv[node];
        }
    }
}

// ---------------- fused layer-1 aggregate + relu + W2 dot ----------------
// one wave (64 lanes) per node; lane handles features {lane, lane+64}
__global__ __launch_bounds__(256) void k_agg1(
    const float* __restrict__ g1, const float* __restrict__ dinv,
    const int* __restrict__ rowstart, const int* __restrict__ counts,
    const int* __restrict__ ebuf,
    const float* __restrict__ b1, const float* __restrict__ W2,
    float* __restrict__ g2, int n) {
    const int lane = threadIdx.x & 63;
    const int node = blockIdx.x * 4 + (threadIdx.x >> 6);
    if (node >= n) return;

    const int start = rowstart[node];
    const int cnt = counts[node];
    const int* __restrict__ eb = ebuf + start;
    const bool hi = (lane < H1 - 64);  // lane < 36

    // self-loop term
    float p0 = g1[(long)node * H1 + lane], p1 = 0.f, p2 = 0.f, p3 = 0.f;
    float q0 = hi ? g1[(long)node * H1 + 64 + lane] : 0.f, q1 = 0.f, q2 = 0.f, q3 = 0.f;

    int j = 0;
    for (; j + 4 <= cnt; j += 4) {
        const long u0 = (long)eb[j] * H1;
        const long u1 = (long)eb[j + 1] * H1;
        const long u2 = (long)eb[j + 2] * H1;
        const long u3 = (long)eb[j + 3] * H1;
        p0 += g1[u0 + lane];
        p1 += g1[u1 + lane];
        p2 += g1[u2 + lane];
        p3 += g1[u3 + lane];
        if (hi) {
            q0 += g1[u0 + 64 + lane];
            q1 += g1[u1 + 64 + lane];
            q2 += g1[u2 + 64 + lane];
            q3 += g1[u3 + 64 + lane];
        }
    }
    for (; j < cnt; ++j) {
        const long u = (long)eb[j] * H1;
        p0 += g1[u + lane];
        if (hi) q0 += g1[u + 64 + lane];
    }

    const float di = dinv[node];
    const float s0 = (p0 + p1) + (p2 + p3);
    const float s1 = (q0 + q1) + (q2 + q3);

    float sum = fmaxf(fmaf(di, s0, b1[lane]), 0.f) * W2[lane];
    if (hi) sum += fmaxf(fmaf(di, s1, b1[64 + lane]), 0.f) * W2[64 + lane];

    #pragma unroll
    for (int off = 32; off > 0; off >>= 1) sum += __shfl_down(sum, off);
    if (lane == 0) g2[node] = di * sum;  // g2 = dinv * h2
}

// ---------------- fused layer-2 aggregate + final bias ----------------
__global__ __launch_bounds__(256) void k_agg2(
    const float* __restrict__ g2, const float* __restrict__ dinv,
    const int* __restrict__ rowstart, const int* __restrict__ counts,
    const int* __restrict__ ebuf, const float* __restrict__ b2,
    float* __restrict__ out, int n) {
    const int lane = threadIdx.x & 63;
    const int node = blockIdx.x * 4 + (threadIdx.x >> 6);
    if (node >= n) return;
    const int start = rowstart[node];
    const int cnt = counts[node];
    float s = 0.f;
    for (int j = lane; j < cnt; j += 64) s += g2[ebuf[start + j]];
    #pragma unroll
    for (int off = 32; off > 0; off >>= 1) s += __shfl_down(s, off);
    if (lane == 0) out[node] = fmaf(dinv[node], g2[node] + s, b2[0]);
}

extern "C" void kernel_launch(void* const* d_in, const int* in_sizes, int n_in,
                              void* d_out, int out_size, void* d_ws, size_t ws_size,
                              hipStream_t stream) {
    const float* x  = (const float*)d_in[0];
    const int*   ei = (const int*)d_in[1];
    const float* W1 = (const float*)d_in[2];
    const float* b1 = (const float*)d_in[3];
    const float* W2 = (const float*)d_in[4];
    const float* b2 = (const float*)d_in[5];

    const int n = in_sizes[0] / F_IN;  // 100000
    const int E = in_sizes[1] / 2;     // 3200000
    const int* src = ei;
    const int* dst = ei + E;

    // workspace layout
    char* p = (char*)d_ws;
    float* dinv = (float*)p;            p += (size_t)n * 4;
    float* g1   = (float*)p;            p += (size_t)n * H1 * 4;
    float* g2   = (float*)p;            p += (size_t)n * 4;
    int* counts   = (int*)p;            p += (size_t)n * 4;
    int* rowstart = (int*)p;            p += (size_t)n * 4;
    int* cursor   = (int*)p;            p += (size_t)n * 4;
    int* bsum     = (int*)p;            p += 512;
    int* ebuf     = (int*)p;            p += (size_t)E * 4;
    float* out = (float*)d_out;

    const int nb = (n + SCAN_CH - 1) / SCAN_CH;  // 98 <= 128

    // zero counts (histogram) and cursor (fill positions)
    k_zero_i<<<(n + 255) / 256, 256, 0, stream>>>(counts, n);
    k_zero_i<<<(n + 255) / 256, 256, 0, stream>>>(cursor, n);
    k_count<<<(E + 255) / 256, 256, 0, stream>>>(dst, counts, E, n);
    k_dinv<<<(n + 255) / 256, 256, 0, stream>>>(counts, dinv, n);
    k_blocksums<<<nb, SCAN_BLK, 0, stream>>>(counts, bsum, n);
    k_scan_bsums<<<1, 128, 0, stream>>>(bsum, nb);
    k_scan_write<<<nb, SCAN_BLK, 0, stream>>>(counts, bsum, rowstart, n);
    k_fill<<<(E + 255) / 256, 256, 0, stream>>>(src, dst, rowstart, cursor, ebuf, E, n);
    k_gemm1<<<(n + 7) / 8, 128, 0, stream>>>(x, W1, dinv, g1, n);
    k_agg1<<<(n + 3) / 4, 256, 0, stream>>>(g1, dinv, rowstart, counts, ebuf, b1, W2, g2, n);
    k_agg2<<<(n + 3) / 4, 256, 0, stream>>>(g2, dinv, rowstart, counts, ebuf, b2, out, n);
}

// Round 4
// 506.379 us; speedup vs baseline: 3.6671x; 1.3861x over previous
//
#include <hip/hip_runtime.h>

#define F_IN 128
#define H1 100
#define SCAN_BLK 256
#define SCAN_CH 1024  // elements per scan block (4 per thread)

__device__ __forceinline__ float bf2f(unsigned short v) {
    union { unsigned u; float f; } x;
    x.u = ((unsigned)v) << 16;
    return x.f;
}
__device__ __forceinline__ unsigned short f2bf(float f) {
    union { float f; unsigned u; } x;
    x.f = f;
    unsigned u = x.u;
    u += 0x7FFF + ((u >> 16) & 1);  // round-to-nearest-even
    return (unsigned short)(u >> 16);
}

// ---------------- zero int buffers ----------------
__global__ void k_zero_i(int* __restrict__ p, int n) {
    int i = blockIdx.x * blockDim.x + threadIdx.x;
    if (i < n) p[i] = 0;
}

// ---------------- histogram of dst + record per-edge position ----------------
__global__ void k_count(const int* __restrict__ dst, int* __restrict__ counts,
                        int* __restrict__ pos, int E, int n) {
    int i = blockIdx.x * blockDim.x + threadIdx.x;
    if (i < E) {
        unsigned d = (unsigned)dst[i];
        if (d >= (unsigned)n) d = 0;  // defensive clamp
        pos[i] = atomicAdd(&counts[d], 1);
    }
}

// ---------------- dinv = rsqrt(1 + count) ----------------
__global__ void k_dinv(const int* __restrict__ counts, float* __restrict__ dinv, int n) {
    int i = blockIdx.x * blockDim.x + threadIdx.x;
    if (i < n) dinv[i] = rsqrtf(1.0f + (float)counts[i]);
}

// ---------------- prefix-scan pass A: per-block sums ----------------
__global__ __launch_bounds__(SCAN_BLK) void k_blocksums(const int* __restrict__ counts,
                                                        int* __restrict__ bsum, int n) {
    __shared__ int sd[SCAN_BLK];
    const int tid = threadIdx.x;
    const int base = blockIdx.x * SCAN_CH + tid * 4;
    int s = 0;
    #pragma unroll
    for (int j = 0; j < 4; ++j) {
        int i = base + j;
        if (i < n) s += counts[i];
    }
    sd[tid] = s;
    __syncthreads();
    for (int off = SCAN_BLK / 2; off > 0; off >>= 1) {
        if (tid < off) sd[tid] += sd[tid + off];
        __syncthreads();
    }
    if (tid == 0) bsum[blockIdx.x] = sd[0];
}

// ---------------- pass B: exclusive scan of block sums (nb <= 128) ----------------
__global__ __launch_bounds__(128) void k_scan_bsums(int* __restrict__ bsum, int nb) {
    __shared__ int sd[128];
    const int tid = threadIdx.x;
    const int v = (tid < nb) ? bsum[tid] : 0;
    sd[tid] = v;
    __syncthreads();
    for (int off = 1; off < 128; off <<= 1) {
        int t = (tid >= off) ? sd[tid - off] : 0;
        __syncthreads();
        sd[tid] += t;
        __syncthreads();
    }
    if (tid < nb) bsum[tid] = sd[tid] - v;  // exclusive
}

// ---------------- pass C: write rowstart ----------------
__global__ __launch_bounds__(SCAN_BLK) void k_scan_write(const int* __restrict__ counts,
                                                         const int* __restrict__ bsum,
                                                         int* __restrict__ rowstart, int n) {
    __shared__ int sd[SCAN_BLK];
    const int tid = threadIdx.x;
    const int base = blockIdx.x * SCAN_CH + tid * 4;
    int c[4];
    int s = 0;
    #pragma unroll
    for (int j = 0; j < 4; ++j) {
        int i = base + j;
        c[j] = (i < n) ? counts[i] : 0;
        s += c[j];
    }
    const int own = s;
    sd[tid] = s;
    __syncthreads();
    for (int off = 1; off < SCAN_BLK; off <<= 1) {
        int t = (tid >= off) ? sd[tid - off] : 0;
        __syncthreads();
        sd[tid] += t;
        __syncthreads();
    }
    int pre = sd[tid] - own + bsum[blockIdx.x];
    #pragma unroll
    for (int j = 0; j < 4; ++j) {
        int i = base + j;
        if (i < n) {
            rowstart[i] = pre;
            pre += c[j];
        }
    }
}

// ---------------- CSR fill (atomic-free): ebuf[rowstart[d]+pos[e]] = src[e] ----
__global__ void k_fill(const int* __restrict__ src, const int* __restrict__ dst,
                       const int* __restrict__ pos, const int* __restrict__ rowstart,
                       int* __restrict__ ebuf, int E, int n) {
    int i = blockIdx.x * blockDim.x + threadIdx.x;
    if (i < E) {
        unsigned d = (unsigned)dst[i];
        unsigned s = (unsigned)src[i];
        if (d >= (unsigned)n) d = 0;
        if (s >= (unsigned)n) s = 0;
        ebuf[rowstart[d] + pos[i]] = (int)s;
    }
}

// ---------------- layer-1 GEMM: g1 = bf16( dinv * (x @ W1) ) ----------------
// block: 128 threads (f = tid, active f < 100), 8 nodes per block.
__global__ __launch_bounds__(128) void k_gemm1(
    const float* __restrict__ x, const float* __restrict__ W1,
    const float* __restrict__ dinv, unsigned short* __restrict__ g, int n) {
    __shared__ float xs[8][F_IN];
    const int f = threadIdx.x;
    const int nb = blockIdx.x * 8;

    {
        const float4* xv = (const float4*)(x + (long)nb * F_IN);
        float4* xsv = (float4*)&xs[0][0];
        #pragma unroll
        for (int i = threadIdx.x; i < 256; i += 128) {
            int node = nb + (i >> 5);
            xsv[i] = (node < n) ? xv[i] : make_float4(0.f, 0.f, 0.f, 0.f);
        }
    }
    __syncthreads();

    const bool act = (f < H1);
    float accv[8] = {0, 0, 0, 0, 0, 0, 0, 0};

    for (int kc = 0; kc < F_IN; kc += 8) {
        float w[8];
        #pragma unroll
        for (int j = 0; j < 8; ++j) w[j] = act ? W1[(kc + j) * H1 + f] : 0.0f;
        #pragma unroll
        for (int v = 0; v < 8; ++v) {
            const float4 b0 = *(const float4*)&xs[v][kc];
            const float4 b1 = *(const float4*)&xs[v][kc + 4];
            float s = accv[v];
            s = fmaf(b0.x, w[0], s);
            s = fmaf(b0.y, w[1], s);
            s = fmaf(b0.z, w[2], s);
            s = fmaf(b0.w, w[3], s);
            s = fmaf(b1.x, w[4], s);
            s = fmaf(b1.y, w[5], s);
            s = fmaf(b1.z, w[6], s);
            s = fmaf(b1.w, w[7], s);
            accv[v] = s;
        }
    }

    if (act) {
        #pragma unroll
        for (int v = 0; v < 8; ++v) {
            int node = nb + v;
            if (node < n) g[node * H1 + f] = f2bf(accv[v] * dinv[node]);
        }
    }
}

// ---------------- fused layer-1 aggregate + relu + W2 dot (bf16 gather) ----------
// one wave (64 lanes) per node; lane handles features {lane, lane+64}
__global__ __launch_bounds__(256) void k_agg1(
    const unsigned short* __restrict__ g1, const float* __restrict__ dinv,
    const int* __restrict__ rowstart, const int* __restrict__ counts,
    const int* __restrict__ ebuf,
    const float* __restrict__ b1, const float* __restrict__ W2,
    float* __restrict__ g2, int n) {
    const int lane = threadIdx.x & 63;
    const int node = blockIdx.x * 4 + (threadIdx.x >> 6);
    if (node >= n) return;

    const int start = rowstart[node];
    const int cnt = counts[node];
    const int* __restrict__ eb = ebuf + start;
    const bool hi = (lane < H1 - 64);  // lane < 36

    // self-loop term
    const int sb = node * H1;
    float p0 = bf2f(g1[sb + lane]), p1 = 0.f, p2 = 0.f, p3 = 0.f;
    float p4 = 0.f, p5 = 0.f, p6 = 0.f, p7 = 0.f;
    float q0 = hi ? bf2f(g1[sb + 64 + lane]) : 0.f, q1 = 0.f, q2 = 0.f, q3 = 0.f;
    float q4 = 0.f, q5 = 0.f, q6 = 0.f, q7 = 0.f;

    int j = 0;
    for (; j + 8 <= cnt; j += 8) {
        const int u0 = eb[j] * H1;
        const int u1 = eb[j + 1] * H1;
        const int u2 = eb[j + 2] * H1;
        const int u3 = eb[j + 3] * H1;
        const int u4 = eb[j + 4] * H1;
        const int u5 = eb[j + 5] * H1;
        const int u6 = eb[j + 6] * H1;
        const int u7 = eb[j + 7] * H1;
        p0 += bf2f(g1[u0 + lane]);
        p1 += bf2f(g1[u1 + lane]);
        p2 += bf2f(g1[u2 + lane]);
        p3 += bf2f(g1[u3 + lane]);
        p4 += bf2f(g1[u4 + lane]);
        p5 += bf2f(g1[u5 + lane]);
        p6 += bf2f(g1[u6 + lane]);
        p7 += bf2f(g1[u7 + lane]);
        if (hi) {
            q0 += bf2f(g1[u0 + 64 + lane]);
            q1 += bf2f(g1[u1 + 64 + lane]);
            q2 += bf2f(g1[u2 + 64 + lane]);
            q3 += bf2f(g1[u3 + 64 + lane]);
            q4 += bf2f(g1[u4 + 64 + lane]);
            q5 += bf2f(g1[u5 + 64 + lane]);
            q6 += bf2f(g1[u6 + 64 + lane]);
            q7 += bf2f(g1[u7 + 64 + lane]);
        }
    }
    for (; j < cnt; ++j) {
        const int u = eb[j] * H1;
        p0 += bf2f(g1[u + lane]);
        if (hi) q0 += bf2f(g1[u + 64 + lane]);
    }

    const float di = dinv[node];
    const float s0 = ((p0 + p1) + (p2 + p3)) + ((p4 + p5) + (p6 + p7));
    const float s1 = ((q0 + q1) + (q2 + q3)) + ((q4 + q5) + (q6 + q7));

    float sum = fmaxf(fmaf(di, s0, b1[lane]), 0.f) * W2[lane];
    if (hi) sum += fmaxf(fmaf(di, s1, b1[64 + lane]), 0.f) * W2[64 + lane];

    #pragma unroll
    for (int off = 32; off > 0; off >>= 1) sum += __shfl_down(sum, off);
    if (lane == 0) g2[node] = di * sum;  // g2 = dinv * h2
}

// ---------------- fused layer-2 aggregate + final bias ----------------
__global__ __launch_bounds__(256) void k_agg2(
    const float* __restrict__ g2, const float* __restrict__ dinv,
    const int* __restrict__ rowstart, const int* __restrict__ counts,
    const int* __restrict__ ebuf, const float* __restrict__ b2,
    float* __restrict__ out, int n) {
    const int lane = threadIdx.x & 63;
    const int node = blockIdx.x * 4 + (threadIdx.x >> 6);
    if (node >= n) return;
    const int start = rowstart[node];
    const int cnt = counts[node];
    float s = 0.f;
    for (int j = lane; j < cnt; j += 64) s += g2[ebuf[start + j]];
    #pragma unroll
    for (int off = 32; off > 0; off >>= 1) s += __shfl_down(s, off);
    if (lane == 0) out[node] = fmaf(dinv[node], g2[node] + s, b2[0]);
}

extern "C" void kernel_launch(void* const* d_in, const int* in_sizes, int n_in,
                              void* d_out, int out_size, void* d_ws, size_t ws_size,
                              hipStream_t stream) {
    const float* x  = (const float*)d_in[0];
    const int*   ei = (const int*)d_in[1];
    const float* W1 = (const float*)d_in[2];
    const float* b1 = (const float*)d_in[3];
    const float* W2 = (const float*)d_in[4];
    const float* b2 = (const float*)d_in[5];

    const int n = in_sizes[0] / F_IN;  // 100000
    const int E = in_sizes[1] / 2;     // 3200000
    const int* src = ei;
    const int* dst = ei + E;

    // workspace layout
    char* p = (char*)d_ws;
    float* dinv = (float*)p;              p += (size_t)n * 4;
    unsigned short* g1 = (unsigned short*)p; p += (size_t)n * H1 * 2;
    p = (char*)(((size_t)p + 15) & ~(size_t)15);
    float* g2   = (float*)p;              p += (size_t)n * 4;
    int* counts   = (int*)p;              p += (size_t)n * 4;
    int* rowstart = (int*)p;              p += (size_t)n * 4;
    int* bsum     = (int*)p;              p += 512;
    int* pos      = (int*)p;              p += (size_t)E * 4;
    int* ebuf     = (int*)p;              p += (size_t)E * 4;
    float* out = (float*)d_out;

    const int nb = (n + SCAN_CH - 1) / SCAN_CH;  // 98 <= 128

    k_zero_i<<<(n + 255) / 256, 256, 0, stream>>>(counts, n);
    k_count<<<(E + 255) / 256, 256, 0, stream>>>(dst, counts, pos, E, n);
    k_dinv<<<(n + 255) / 256, 256, 0, stream>>>(counts, dinv, n);
    k_blocksums<<<nb, SCAN_BLK, 0, stream>>>(counts, bsum, n);
    k_scan_bsums<<<1, 128, 0, stream>>>(bsum, nb);
    k_scan_write<<<nb, SCAN_BLK, 0, stream>>>(counts, bsum, rowstart, n);
    k_fill<<<(E + 255) / 256, 256, 0, stream>>>(src, dst, pos, rowstart, ebuf, E, n);
    k_gemm1<<<(n + 7) / 8, 128, 0, stream>>>(x, W1, dinv, g1, n);
    k_agg1<<<(n + 3) / 4, 256, 0, stream>>>(g1, dinv, rowstart, counts, ebuf, b1, W2, g2, n);
    k_agg2<<<(n + 3) / 4, 256, 0, stream>>>(g2, dinv, rowstart, counts, ebuf, b2, out, n);
}